// Round 19
// baseline (617.637 us; speedup 1.0000x reference)
//
#include <hip/hip_runtime.h>
#include <hip/hip_bf16.h>

#define DIM 256
#define HEADS 4
#define NEG_SLOPE 0.01f

typedef unsigned short u16;
typedef __attribute__((ext_vector_type(8))) short short8;
typedef __attribute__((ext_vector_type(4))) float f32x4;
typedef __attribute__((ext_vector_type(4))) unsigned short u16x4;

// ---- bf16 helpers ----
__device__ __forceinline__ u16 f2bf(float f) {           // RTN-even
    unsigned u = __float_as_uint(f);
    unsigned r = (u + 0x7fffu + ((u >> 16) & 1u)) >> 16;
    return (u16)r;
}
__device__ __forceinline__ float bf2f(u16 h) {
    return __uint_as_float(((unsigned)h) << 16);
}
__device__ __forceinline__ unsigned cvt2(float a, float b) {   // native v_cvt_pk path
    __hip_bfloat162 h = __float22bfloat162_rn(make_float2(a, b));
    unsigned u;
    __builtin_memcpy(&u, &h, 4);
    return u;
}

// K0: transpose w_q (k-major fp32) -> BThi (n-major bf16, RTN)
__global__ __launch_bounds__(256) void prepb_kernel(const float* __restrict__ B,
                                                    u16* __restrict__ BThi) {
    int k = blockIdx.x;
    int n = threadIdx.x;
    BThi[n * 256 + k] = f2bf(B[k * 256 + n]);
}

// K1: beta[j,h] = sum_{d<64} x_edge[j, h*64+d] * weight[h, d]
__global__ __launch_bounds__(256) void beta_kernel(const float* __restrict__ xe,
                                                   const float* __restrict__ weight,
                                                   float* __restrict__ beta, int NE) {
    int wid = blockIdx.x * 4 + (threadIdx.x >> 6);
    if (wid >= NE) return;
    int lane = threadIdx.x & 63;
    int h = lane >> 4;
    float4 v = *reinterpret_cast<const float4*>(xe + (size_t)wid * DIM + lane * 4);
    float4 w = *reinterpret_cast<const float4*>(weight + h * 128 + (lane & 15) * 4);
    float p = v.x * w.x + v.y * w.y + v.z * w.z + v.w * w.w;
    p += __shfl_xor(p, 1);
    p += __shfl_xor(p, 2);
    p += __shfl_xor(p, 4);
    p += __shfl_xor(p, 8);
    if ((lane & 15) == 0) beta[(size_t)wid * 4 + h] = p;
}

// K2: xq = x_q @ w_q via bf16 MFMA. BM=32 (grid 15625, 5 blocks/CU -> more
// independent HBM burst streams), BK=128. A staging fully coalesced: chunk
// g = t + i*256 -> row g>>5, col g&31 (each wave-instr = 1KB contiguous).
// LDS [32][128] bf16, 16B-chunk swizzle pc = lc ^ (row&15).
// B: direct global->reg fragments (L2-resident). Fused epilogue.
__global__ __launch_bounds__(256, 5) void gemm_fused_kernel(const float* __restrict__ A,
                                                            const u16* __restrict__ BThi,
                                                            const float* __restrict__ weight,
                                                            const float* __restrict__ beta,
                                                            const int* __restrict__ eids,
                                                            u16* __restrict__ xq_out,
                                                            float* __restrict__ exv,
                                                            float* __restrict__ segsum,
                                                            unsigned* __restrict__ counts,
                                                            int NQ) {
    __shared__ u16 A_s[32 * 128];   // 8 KB

    const int t = threadIdx.x;
    const int lane = t & 63;
    const int wc = t >> 6;         // wave = head / 64-col group
    const int lr = lane & 15;
    const int kg = lane >> 4;
    const long brow = (long)blockIdx.x * 32;

    // coalesced staging: chunk g = t + i*256 -> row = g>>5, col16 = g&31
    const float* asrc[4];
    int arow[4], acol[4];
#pragma unroll
    for (int i = 0; i < 4; ++i) {
        int g = t + i * 256;
        int row = g >> 5, col = g & 31;
        long grow = brow + row;
        if (grow >= NQ) grow = NQ - 1;
        asrc[i] = A + grow * DIM + col * 4;
        arow[i] = row;
        acol[i] = col;
    }

    // B fragment pointers (direct from L2)
    const u16* brows[4];
#pragma unroll
    for (int n = 0; n < 4; ++n)
        brows[n] = BThi + (wc * 64 + n * 16 + lr) * 256 + kg * 8;

    f32x4 acc[2][4];
#pragma unroll
    for (int m = 0; m < 2; ++m)
#pragma unroll
        for (int n = 0; n < 4; ++n) acc[m][n] = (f32x4){0.f, 0.f, 0.f, 0.f};

#pragma unroll 1
    for (int k0 = 0; k0 < DIM; k0 += 128) {
        // burst-load 4 contiguous-coalesced 16B chunks of A
        float4 ar[4];
#pragma unroll
        for (int i = 0; i < 4; ++i)
            ar[i] = *reinterpret_cast<const float4*>(asrc[i] + k0);
        if (k0) __syncthreads();   // all waves done reading previous tile
        // convert + write swizzled 8B half-chunks
#pragma unroll
        for (int i = 0; i < 4; ++i) {
            uint2 wv = make_uint2(cvt2(ar[i].x, ar[i].y), cvt2(ar[i].z, ar[i].w));
            int row = arow[i];
            int pc = (acol[i] >> 1) ^ (row & 15);
            *reinterpret_cast<uint2*>(&A_s[row * 128 + pc * 8 + (acol[i] & 1) * 4]) = wv;
        }
        __syncthreads();
        // compute 4 k-subtiles of 32
#pragma unroll
        for (int s = 0; s < 4; ++s) {
            short8 bh[4];
#pragma unroll
            for (int n = 0; n < 4; ++n)
                bh[n] = *reinterpret_cast<const short8*>(brows[n] + k0 + s * 32);
#pragma unroll
            for (int m = 0; m < 2; ++m) {
                int rr = m * 16 + lr;
                int pc = (s * 4 + kg) ^ (rr & 15);
                short8 ah = *reinterpret_cast<const short8*>(&A_s[rr * 128 + pc * 8]);
#pragma unroll
                for (int n = 0; n < 4; ++n)
                    acc[m][n] = __builtin_amdgcn_mfma_f32_16x16x32_bf16(ah, bh[n], acc[m][n], 0, 0, 0);
            }
        }
    }

    // epilogue: bf16 xq stores + per-head gamma -> ex -> segsum/counts
    float wv[4];
#pragma unroll
    for (int n = 0; n < 4; ++n) wv[n] = weight[wc * 128 + 64 + n * 16 + lr];

#pragma unroll
    for (int m = 0; m < 2; ++m) {
#pragma unroll
        for (int r = 0; r < 4; ++r) {
            long row = brow + m * 16 + kg * 4 + r;
            bool ok = row < NQ;
            float p = 0.f;
#pragma unroll
            for (int n = 0; n < 4; ++n) {
                float v = acc[m][n][r];
                if (ok) xq_out[row * DIM + wc * 64 + n * 16 + lr] = f2bf(v);
                p = fmaf(v, wv[n], p);
            }
            p += __shfl_xor(p, 1);
            p += __shfl_xor(p, 2);
            p += __shfl_xor(p, 4);
            p += __shfl_xor(p, 8);
            if (ok && lr == 0) {
                int j = eids[row];
                float l = beta[(size_t)j * 4 + wc] + p;
                l = l > 0.f ? l : NEG_SLOPE * l;
                float e = __expf(l);
                exv[row * 4 + wc] = e;
                atomicAdd(&segsum[(size_t)j * 4 + wc], e);
                if (wc == 0) atomicAdd(&counts[j], 1u);
            }
        }
    }
}

// ---- CSR build ----
__global__ __launch_bounds__(256) void scan1_kernel(const unsigned* __restrict__ counts,
                                                    unsigned* __restrict__ offs,
                                                    unsigned* __restrict__ blocksums, int NE) {
    __shared__ unsigned s[256];
    int t = threadIdx.x;
    int base = blockIdx.x * 1024 + t * 4;
    unsigned v[4], sum = 0;
#pragma unroll
    for (int i = 0; i < 4; ++i) {
        v[i] = (base + i < NE) ? counts[base + i] : 0u;
        sum += v[i];
    }
    s[t] = sum;
    __syncthreads();
    for (int off = 1; off < 256; off <<= 1) {
        unsigned y = (t >= off) ? s[t - off] : 0u;
        __syncthreads();
        s[t] += y;
        __syncthreads();
    }
    unsigned excl = s[t] - sum;
#pragma unroll
    for (int i = 0; i < 4; ++i) {
        if (base + i < NE) offs[base + i] = excl;
        excl += v[i];
    }
    if (t == 255) blocksums[blockIdx.x] = s[255];
}

__global__ __launch_bounds__(256) void scan2_kernel(unsigned* __restrict__ blocksums, int NB) {
    __shared__ unsigned s[256];
    int t = threadIdx.x;
    unsigned v = (t < NB) ? blocksums[t] : 0u;
    s[t] = v;
    __syncthreads();
    for (int off = 1; off < 256; off <<= 1) {
        unsigned y = (t >= off) ? s[t - off] : 0u;
        __syncthreads();
        s[t] += y;
        __syncthreads();
    }
    if (t < NB) blocksums[t] = s[t] - v;
}

__global__ __launch_bounds__(256) void scan3_kernel(unsigned* __restrict__ offs,
                                                    const unsigned* __restrict__ blocksums,
                                                    unsigned* __restrict__ cursor, int NE) {
    int t = threadIdx.x;
    int base = blockIdx.x * 1024 + t * 4;
    unsigned add = blocksums[blockIdx.x];
#pragma unroll
    for (int i = 0; i < 4; ++i) {
        if (base + i < NE) {
            unsigned o = offs[base + i] + add;
            offs[base + i] = o;
            cursor[base + i] = o;
        }
    }
}

__global__ __launch_bounds__(256) void fill_kernel(const int* __restrict__ eids,
                                                   unsigned* __restrict__ cursor,
                                                   int* __restrict__ qlist, int NQ) {
    int e = blockIdx.x * blockDim.x + threadIdx.x;
    if (e >= NQ) return;
    int j = eids[e];
    unsigned pos = atomicAdd(&cursor[j], 1u);
    qlist[pos] = e;
}

// gather: out[j,:] = sum_{q in seg(j)} (ex[q,h]/(segsum[j,h]+eps)) * xq_bf16[q,:]
__global__ __launch_bounds__(256) void gather_kernel(const float* __restrict__ exv,
                                                     const float* __restrict__ segsum,
                                                     const unsigned* __restrict__ offs,
                                                     const unsigned* __restrict__ counts,
                                                     const int* __restrict__ qlist,
                                                     const u16* __restrict__ xq,
                                                     float* __restrict__ out, int NE) {
    int j = blockIdx.x * 4 + (threadIdx.x >> 6);
    if (j >= NE) return;
    int lane = threadIdx.x & 63;
    int h = lane >> 4;
    unsigned beg = offs[j];
    unsigned n = counts[j];
    float inv = 1.0f / (segsum[(size_t)j * 4 + h] + 1e-16f);
    float4 a0 = make_float4(0.f, 0.f, 0.f, 0.f);
    float4 a1 = make_float4(0.f, 0.f, 0.f, 0.f);
    unsigned i = 0;
    for (; i + 2 <= n; i += 2) {
        int q0 = qlist[beg + i];
        int q1 = qlist[beg + i + 1];
        float w0 = exv[(size_t)q0 * 4 + h] * inv;
        float w1 = exv[(size_t)q1 * 4 + h] * inv;
        u16x4 v0 = *reinterpret_cast<const u16x4*>(xq + (size_t)q0 * DIM + lane * 4);
        u16x4 v1 = *reinterpret_cast<const u16x4*>(xq + (size_t)q1 * DIM + lane * 4);
        a0.x = fmaf(w0, bf2f(v0.x), a0.x); a1.x = fmaf(w1, bf2f(v1.x), a1.x);
        a0.y = fmaf(w0, bf2f(v0.y), a0.y); a1.y = fmaf(w1, bf2f(v1.y), a1.y);
        a0.z = fmaf(w0, bf2f(v0.z), a0.z); a1.z = fmaf(w1, bf2f(v1.z), a1.z);
        a0.w = fmaf(w0, bf2f(v0.w), a0.w); a1.w = fmaf(w1, bf2f(v1.w), a1.w);
    }
    if (i < n) {
        int q0 = qlist[beg + i];
        float w0 = exv[(size_t)q0 * 4 + h] * inv;
        u16x4 v0 = *reinterpret_cast<const u16x4*>(xq + (size_t)q0 * DIM + lane * 4);
        a0.x = fmaf(w0, bf2f(v0.x), a0.x);
        a0.y = fmaf(w0, bf2f(v0.y), a0.y);
        a0.z = fmaf(w0, bf2f(v0.z), a0.z);
        a0.w = fmaf(w0, bf2f(v0.w), a0.w);
    }
    float4 acc = make_float4(a0.x + a1.x, a0.y + a1.y, a0.z + a1.z, a0.w + a1.w);
    *reinterpret_cast<float4*>(out + (size_t)j * DIM + lane * 4) = acc;
}

extern "C" void kernel_launch(void* const* d_in, const int* in_sizes, int n_in,
                              void* d_out, int out_size, void* d_ws, size_t ws_size,
                              hipStream_t stream) {
    (void)n_in; (void)out_size; (void)ws_size;
    const float* x_q    = (const float*)d_in[0];
    const float* x_edge = (const float*)d_in[1];
    const float* w_q    = (const float*)d_in[2];
    const float* weight = (const float*)d_in[3];
    const int*   eids   = (const int*)d_in[4];
    const int NQ = in_sizes[0] / DIM;   // 500000
    const int NE = in_sizes[1] / DIM;   // 250000
    float* out = (float*)d_out;

    // workspace layout
    u16*      xq        = (u16*)d_ws;                           // NQ*256 bf16
    float*    exv       = (float*)(xq + (size_t)NQ * DIM);      // NQ*4
    float*    beta      = exv + (size_t)NQ * 4;                 // NE*4
    float*    segsum    = beta + (size_t)NE * 4;                // NE*4
    unsigned* counts    = (unsigned*)(segsum + (size_t)NE * 4); // NE
    unsigned* offs      = counts + NE;                          // NE
    unsigned* cursor    = offs + NE;                            // NE
    int*      qlist     = (int*)(cursor + NE);                  // NQ
    unsigned* blocksums = (unsigned*)(qlist + NQ);              // 256
    u16*      BThi      = (u16*)(blocksums + 256);              // 256*256

    const int NB = (NE + 1023) / 1024;

    hipMemsetAsync(segsum, 0, (size_t)NE * 4 * sizeof(float), stream);
    hipMemsetAsync(counts, 0, (size_t)NE * sizeof(unsigned), stream);

    prepb_kernel<<<256, 256, 0, stream>>>(w_q, BThi);
    beta_kernel<<<(NE + 3) / 4, 256, 0, stream>>>(x_edge, weight, beta, NE);
    gemm_fused_kernel<<<(NQ + 31) / 32, 256, 0, stream>>>(x_q, BThi, weight, beta, eids,
                                                          xq, exv, segsum, counts, NQ);
    scan1_kernel<<<NB, 256, 0, stream>>>(counts, offs, blocksums, NE);
    scan2_kernel<<<1, 256, 0, stream>>>(blocksums, NB);
    scan3_kernel<<<NB, 256, 0, stream>>>(offs, blocksums, cursor, NE);
    fill_kernel<<<(NQ + 255) / 256, 256, 0, stream>>>(eids, cursor, qlist, NQ);
    gather_kernel<<<(NE + 3) / 4, 256, 0, stream>>>(exv, segsum, offs, counts, qlist, xq, out, NE);
}

// Round 20
// 584.201 us; speedup vs baseline: 1.0572x; 1.0572x over previous
//
#include <hip/hip_runtime.h>
#include <hip/hip_bf16.h>

#define DIM 256
#define HEADS 4
#define NEG_SLOPE 0.01f

typedef unsigned short u16;
typedef __attribute__((ext_vector_type(8))) short short8;
typedef __attribute__((ext_vector_type(4))) float f32x4;
typedef __attribute__((ext_vector_type(4))) unsigned short u16x4;

// ---- bf16 helpers ----
__device__ __forceinline__ u16 f2bf(float f) {           // RTN-even
    unsigned u = __float_as_uint(f);
    unsigned r = (u + 0x7fffu + ((u >> 16) & 1u)) >> 16;
    return (u16)r;
}
__device__ __forceinline__ float bf2f(u16 h) {
    return __uint_as_float(((unsigned)h) << 16);
}
__device__ __forceinline__ unsigned cvt2(float a, float b) {   // native v_cvt_pk path
    __hip_bfloat162 h = __float22bfloat162_rn(make_float2(a, b));
    unsigned u;
    __builtin_memcpy(&u, &h, 4);
    return u;
}

// K0: transpose w_q (k-major fp32) -> BThi (n-major bf16, RTN)
__global__ __launch_bounds__(256) void prepb_kernel(const float* __restrict__ B,
                                                    u16* __restrict__ BThi) {
    int k = blockIdx.x;
    int n = threadIdx.x;
    BThi[n * 256 + k] = f2bf(B[k * 256 + n]);
}

// K1: beta[j,h] = sum_{d<64} x_edge[j, h*64+d] * weight[h, d]
__global__ __launch_bounds__(256) void beta_kernel(const float* __restrict__ xe,
                                                   const float* __restrict__ weight,
                                                   float* __restrict__ beta, int NE) {
    int wid = blockIdx.x * 4 + (threadIdx.x >> 6);
    if (wid >= NE) return;
    int lane = threadIdx.x & 63;
    int h = lane >> 4;
    float4 v = *reinterpret_cast<const float4*>(xe + (size_t)wid * DIM + lane * 4);
    float4 w = *reinterpret_cast<const float4*>(weight + h * 128 + (lane & 15) * 4);
    float p = v.x * w.x + v.y * w.y + v.z * w.z + v.w * w.w;
    p += __shfl_xor(p, 1);
    p += __shfl_xor(p, 2);
    p += __shfl_xor(p, 4);
    p += __shfl_xor(p, 8);
    if ((lane & 15) == 0) beta[(size_t)wid * 4 + h] = p;
}

// K2: xq = x_q @ w_q via bf16 MFMA. 3-deep software pipeline with RAW
// s_barrier (no implicit vmcnt(0) drain) + FIFO-ordered issue so A-prefetch
// loads survive barriers: per step: dswrite(s+1) -> B(s) -> A(s+3) -> MFMA ->
// lgkmcnt(0) -> s_barrier. A: LDS dbuf bf16 (r12 swizzle). B: direct L2.
// Fused epilogue: gamma -> logit -> ex -> exv/segsum/counts.
__global__ __launch_bounds__(256, 3) void gemm_fused_kernel(const float* __restrict__ A,
                                                            const u16* __restrict__ BThi,
                                                            const float* __restrict__ weight,
                                                            const float* __restrict__ beta,
                                                            const int* __restrict__ eids,
                                                            u16* __restrict__ xq_out,
                                                            float* __restrict__ exv,
                                                            float* __restrict__ segsum,
                                                            unsigned* __restrict__ counts,
                                                            int NQ) {
    __shared__ u16 A_s[2][64 * 32];   // 8 KB dbuf

    const int t = threadIdx.x;
    const int lane = t & 63;
    const int wc = t >> 6;
    const int lr = lane & 15;
    const int kg = lane >> 4;
    const long brow = (long)blockIdx.x * 64;

    // A staging geometry: thread covers rows s_row0 and s_row0+32, 1 float4 each
    const int s_row0 = t >> 3, s_c4 = t & 7;
    const float* aptr0;
    const float* aptr1;
    {
        long g0 = brow + s_row0;       if (g0 >= NQ) g0 = NQ - 1;
        long g1 = brow + s_row0 + 32;  if (g1 >= NQ) g1 = NQ - 1;
        aptr0 = A + g0 * DIM + s_c4 * 4;
        aptr1 = A + g1 * DIM + s_c4 * 4;
    }
    // precomputed swizzled staging offsets (r12's proven swizzle)
    const int off_w0 = s_row0 * 32 + ((((s_c4 >> 1) ^ (s_row0 & 3) ^ ((s_row0 >> 2) & 3))) << 3) + ((s_c4 & 1) << 2);
    const int s_row1 = s_row0 + 32;
    const int off_w1 = s_row1 * 32 + ((((s_c4 >> 1) ^ (s_row1 & 3) ^ ((s_row1 >> 2) & 3))) << 3) + ((s_c4 & 1) << 2);

    // B fragment pointers (direct from L2)
    const u16* brows[4];
#pragma unroll
    for (int n = 0; n < 4; ++n)
        brows[n] = BThi + (wc * 64 + n * 16 + lr) * 256 + kg * 8;

    // MFMA-side LDS read offsets (static per thread)
    int rdoff[4];
#pragma unroll
    for (int m = 0; m < 4; ++m) {
        int rr = m * 16 + lr;
        rdoff[m] = rr * 32 + ((kg ^ (rr & 3) ^ ((rr >> 2) & 3)) << 3);
    }

    f32x4 acc[4][4];
#pragma unroll
    for (int m = 0; m < 4; ++m)
#pragma unroll
        for (int n = 0; n < 4; ++n) acc[m][n] = (f32x4){0.f, 0.f, 0.f, 0.f};

    // 3 register sets for 3-deep A prefetch (static indices only)
    float4 areg[3][2];

    // prologue: issue A loads for tiles 0,1,2; write tile0 into buf0
#pragma unroll
    for (int s0 = 0; s0 < 3; ++s0) {
        areg[s0][0] = *reinterpret_cast<const float4*>(aptr0 + s0 * 32);
        areg[s0][1] = *reinterpret_cast<const float4*>(aptr1 + s0 * 32);
    }
    {
        uint2 w0 = make_uint2(cvt2(areg[0][0].x, areg[0][0].y), cvt2(areg[0][0].z, areg[0][0].w));
        uint2 w1 = make_uint2(cvt2(areg[0][1].x, areg[0][1].y), cvt2(areg[0][1].z, areg[0][1].w));
        *reinterpret_cast<uint2*>(&A_s[0][off_w0]) = w0;
        *reinterpret_cast<uint2*>(&A_s[0][off_w1]) = w1;
    }
    asm volatile("s_waitcnt lgkmcnt(0)" ::: "memory");
    __builtin_amdgcn_s_barrier();

#pragma unroll
    for (int s = 0; s < 8; ++s) {
        const int buf = s & 1;
        // 1. write tile s+1 into buf^1 (vmcnt auto-waits only that tile's loads)
        if (s < 7) {
            const int set = (s + 1) % 3;
            uint2 w0 = make_uint2(cvt2(areg[set][0].x, areg[set][0].y), cvt2(areg[set][0].z, areg[set][0].w));
            uint2 w1 = make_uint2(cvt2(areg[set][1].x, areg[set][1].y), cvt2(areg[set][1].z, areg[set][1].w));
            *reinterpret_cast<uint2*>(&A_s[buf ^ 1][off_w0]) = w0;
            *reinterpret_cast<uint2*>(&A_s[buf ^ 1][off_w1]) = w1;
        }
        // 2. B loads for tile s (older than A prefetch -> counted waits spare A)
        short8 bh0 = *reinterpret_cast<const short8*>(brows[0] + s * 32);
        short8 bh1 = *reinterpret_cast<const short8*>(brows[1] + s * 32);
        short8 bh2 = *reinterpret_cast<const short8*>(brows[2] + s * 32);
        short8 bh3 = *reinterpret_cast<const short8*>(brows[3] + s * 32);
        // 3. A loads for tile s+3 (youngest; survive barrier + B waits)
        if (s < 5) {
            const int set = s % 3;
            areg[set][0] = *reinterpret_cast<const float4*>(aptr0 + (s + 3) * 32);
            areg[set][1] = *reinterpret_cast<const float4*>(aptr1 + (s + 3) * 32);
        }
        // 4. compute tile s from A_s[buf]
#pragma unroll
        for (int m = 0; m < 4; ++m) {
            short8 ah = *reinterpret_cast<const short8*>(&A_s[buf][rdoff[m]]);
            acc[m][0] = __builtin_amdgcn_mfma_f32_16x16x32_bf16(ah, bh0, acc[m][0], 0, 0, 0);
            acc[m][1] = __builtin_amdgcn_mfma_f32_16x16x32_bf16(ah, bh1, acc[m][1], 0, 0, 0);
            acc[m][2] = __builtin_amdgcn_mfma_f32_16x16x32_bf16(ah, bh2, acc[m][2], 0, 0, 0);
            acc[m][3] = __builtin_amdgcn_mfma_f32_16x16x32_bf16(ah, bh3, acc[m][3], 0, 0, 0);
        }
        // 5. LDS visibility + raw barrier (A prefetch stays in flight)
        if (s < 7) {
            asm volatile("s_waitcnt lgkmcnt(0)" ::: "memory");
            __builtin_amdgcn_s_barrier();
        }
    }

    // epilogue: bf16 xq stores + per-head gamma -> ex -> segsum/counts
    float wv[4];
#pragma unroll
    for (int n = 0; n < 4; ++n) wv[n] = weight[wc * 128 + 64 + n * 16 + lr];

#pragma unroll
    for (int m = 0; m < 4; ++m) {
#pragma unroll
        for (int r = 0; r < 4; ++r) {
            long row = brow + m * 16 + kg * 4 + r;
            bool ok = row < NQ;
            float p = 0.f;
#pragma unroll
            for (int n = 0; n < 4; ++n) {
                float v = acc[m][n][r];
                if (ok) xq_out[row * DIM + wc * 64 + n * 16 + lr] = f2bf(v);
                p = fmaf(v, wv[n], p);
            }
            p += __shfl_xor(p, 1);
            p += __shfl_xor(p, 2);
            p += __shfl_xor(p, 4);
            p += __shfl_xor(p, 8);
            if (ok && lr == 0) {
                int j = eids[row];
                float l = beta[(size_t)j * 4 + wc] + p;
                l = l > 0.f ? l : NEG_SLOPE * l;
                float e = __expf(l);
                exv[row * 4 + wc] = e;
                atomicAdd(&segsum[(size_t)j * 4 + wc], e);
                if (wc == 0) atomicAdd(&counts[j], 1u);
            }
        }
    }
}

// ---- CSR build ----
__global__ __launch_bounds__(256) void scan1_kernel(const unsigned* __restrict__ counts,
                                                    unsigned* __restrict__ offs,
                                                    unsigned* __restrict__ blocksums, int NE) {
    __shared__ unsigned s[256];
    int t = threadIdx.x;
    int base = blockIdx.x * 1024 + t * 4;
    unsigned v[4], sum = 0;
#pragma unroll
    for (int i = 0; i < 4; ++i) {
        v[i] = (base + i < NE) ? counts[base + i] : 0u;
        sum += v[i];
    }
    s[t] = sum;
    __syncthreads();
    for (int off = 1; off < 256; off <<= 1) {
        unsigned y = (t >= off) ? s[t - off] : 0u;
        __syncthreads();
        s[t] += y;
        __syncthreads();
    }
    unsigned excl = s[t] - sum;
#pragma unroll
    for (int i = 0; i < 4; ++i) {
        if (base + i < NE) offs[base + i] = excl;
        excl += v[i];
    }
    if (t == 255) blocksums[blockIdx.x] = s[255];
}

__global__ __launch_bounds__(256) void scan2_kernel(unsigned* __restrict__ blocksums, int NB) {
    __shared__ unsigned s[256];
    int t = threadIdx.x;
    unsigned v = (t < NB) ? blocksums[t] : 0u;
    s[t] = v;
    __syncthreads();
    for (int off = 1; off < 256; off <<= 1) {
        unsigned y = (t >= off) ? s[t - off] : 0u;
        __syncthreads();
        s[t] += y;
        __syncthreads();
    }
    if (t < NB) blocksums[t] = s[t] - v;
}

__global__ __launch_bounds__(256) void scan3_kernel(unsigned* __restrict__ offs,
                                                    const unsigned* __restrict__ blocksums,
                                                    unsigned* __restrict__ cursor, int NE) {
    int t = threadIdx.x;
    int base = blockIdx.x * 1024 + t * 4;
    unsigned add = blocksums[blockIdx.x];
#pragma unroll
    for (int i = 0; i < 4; ++i) {
        if (base + i < NE) {
            unsigned o = offs[base + i] + add;
            offs[base + i] = o;
            cursor[base + i] = o;
        }
    }
}

__global__ __launch_bounds__(256) void fill_kernel(const int* __restrict__ eids,
                                                   unsigned* __restrict__ cursor,
                                                   int* __restrict__ qlist, int NQ) {
    int e = blockIdx.x * blockDim.x + threadIdx.x;
    if (e >= NQ) return;
    int j = eids[e];
    unsigned pos = atomicAdd(&cursor[j], 1u);
    qlist[pos] = e;
}

// gather: out[j,:] = sum_{q in seg(j)} (ex[q,h]/(segsum[j,h]+eps)) * xq_bf16[q,:]
__global__ __launch_bounds__(256) void gather_kernel(const float* __restrict__ exv,
                                                     const float* __restrict__ segsum,
                                                     const unsigned* __restrict__ offs,
                                                     const unsigned* __restrict__ counts,
                                                     const int* __restrict__ qlist,
                                                     const u16* __restrict__ xq,
                                                     float* __restrict__ out, int NE) {
    int j = blockIdx.x * 4 + (threadIdx.x >> 6);
    if (j >= NE) return;
    int lane = threadIdx.x & 63;
    int h = lane >> 4;
    unsigned beg = offs[j];
    unsigned n = counts[j];
    float inv = 1.0f / (segsum[(size_t)j * 4 + h] + 1e-16f);
    float4 a0 = make_float4(0.f, 0.f, 0.f, 0.f);
    float4 a1 = make_float4(0.f, 0.f, 0.f, 0.f);
    unsigned i = 0;
    for (; i + 2 <= n; i += 2) {
        int q0 = qlist[beg + i];
        int q1 = qlist[beg + i + 1];
        float w0 = exv[(size_t)q0 * 4 + h] * inv;
        float w1 = exv[(size_t)q1 * 4 + h] * inv;
        u16x4 v0 = *reinterpret_cast<const u16x4*>(xq + (size_t)q0 * DIM + lane * 4);
        u16x4 v1 = *reinterpret_cast<const u16x4*>(xq + (size_t)q1 * DIM + lane * 4);
        a0.x = fmaf(w0, bf2f(v0.x), a0.x); a1.x = fmaf(w1, bf2f(v1.x), a1.x);
        a0.y = fmaf(w0, bf2f(v0.y), a0.y); a1.y = fmaf(w1, bf2f(v1.y), a1.y);
        a0.z = fmaf(w0, bf2f(v0.z), a0.z); a1.z = fmaf(w1, bf2f(v1.z), a1.z);
        a0.w = fmaf(w0, bf2f(v0.w), a0.w); a1.w = fmaf(w1, bf2f(v1.w), a1.w);
    }
    if (i < n) {
        int q0 = qlist[beg + i];
        float w0 = exv[(size_t)q0 * 4 + h] * inv;
        u16x4 v0 = *reinterpret_cast<const u16x4*>(xq + (size_t)q0 * DIM + lane * 4);
        a0.x = fmaf(w0, bf2f(v0.x), a0.x);
        a0.y = fmaf(w0, bf2f(v0.y), a0.y);
        a0.z = fmaf(w0, bf2f(v0.z), a0.z);
        a0.w = fmaf(w0, bf2f(v0.w), a0.w);
    }
    float4 acc = make_float4(a0.x + a1.x, a0.y + a1.y, a0.z + a1.z, a0.w + a1.w);
    *reinterpret_cast<float4*>(out + (size_t)j * DIM + lane * 4) = acc;
}

extern "C" void kernel_launch(void* const* d_in, const int* in_sizes, int n_in,
                              void* d_out, int out_size, void* d_ws, size_t ws_size,
                              hipStream_t stream) {
    (void)n_in; (void)out_size; (void)ws_size;
    const float* x_q    = (const float*)d_in[0];
    const float* x_edge = (const float*)d_in[1];
    const float* w_q    = (const float*)d_in[2];
    const float* weight = (const float*)d_in[3];
    const int*   eids   = (const int*)d_in[4];
    const int NQ = in_sizes[0] / DIM;   // 500000
    const int NE = in_sizes[1] / DIM;   // 250000
    float* out = (float*)d_out;

    // workspace layout
    u16*      xq        = (u16*)d_ws;                           // NQ*256 bf16
    float*    exv       = (float*)(xq + (size_t)NQ * DIM);      // NQ*4
    float*    beta      = exv + (size_t)NQ * 4;                 // NE*4
    float*    segsum    = beta + (size_t)NE * 4;                // NE*4
    unsigned* counts    = (unsigned*)(segsum + (size_t)NE * 4); // NE
    unsigned* offs      = counts + NE;                          // NE
    unsigned* cursor    = offs + NE;                            // NE
    int*      qlist     = (int*)(cursor + NE);                  // NQ
    unsigned* blocksums = (unsigned*)(qlist + NQ);              // 256
    u16*      BThi      = (u16*)(blocksums + 256);              // 256*256

    const int NB = (NE + 1023) / 1024;

    hipMemsetAsync(segsum, 0, (size_t)NE * 4 * sizeof(float), stream);
    hipMemsetAsync(counts, 0, (size_t)NE * sizeof(unsigned), stream);

    prepb_kernel<<<256, 256, 0, stream>>>(w_q, BThi);
    beta_kernel<<<(NE + 3) / 4, 256, 0, stream>>>(x_edge, weight, beta, NE);
    gemm_fused_kernel<<<(NQ + 63) / 64, 256, 0, stream>>>(x_q, BThi, weight, beta, eids,
                                                          xq, exv, segsum, counts, NQ);
    scan1_kernel<<<NB, 256, 0, stream>>>(counts, offs, blocksums, NE);
    scan2_kernel<<<1, 256, 0, stream>>>(blocksums, NB);
    scan3_kernel<<<NB, 256, 0, stream>>>(offs, blocksums, cursor, NE);
    fill_kernel<<<(NQ + 255) / 256, 256, 0, stream>>>(eids, cursor, qlist, NQ);
    gather_kernel<<<(NE + 3) / 4, 256, 0, stream>>>(exv, segsum, offs, counts, qlist, xq, out, NE);
}